// Round 2
// baseline (197.786 us; speedup 1.0000x reference)
//
#include <hip/hip_runtime.h>

// LateralInhibitionAttention, MI355X.
// Conv3x3 of the rank-structured score matrix factorizes:
//   sum_{3x3} s[n+i][m+j] = (q[n-1]+q[n]+q[n+1]) . (k[m-1]+k[m]+k[m+1])
// so inhibited scores = [cq*q ; cs*qsum] . [k ; ksum]  (augmented 128-dim dot)
// with cq = 1.2*D^-0.5, cs = -0.2*D^-0.5 -> plain softmax attention.
// Workspace kept under 28.8 MB (round-1 failure was ws overflow corrupting inputs).

using short8 = __attribute__((ext_vector_type(8))) short;
using short4v = __attribute__((ext_vector_type(4))) short;
using f32x4 = __attribute__((ext_vector_type(4))) float;

#define MFMA16(a, b, c) __builtin_amdgcn_mfma_f32_16x16x32_bf16((a), (b), (c), 0, 0, 0)

__device__ __forceinline__ float b2f(short s) {
    union { unsigned u; float f; } x;
    x.u = ((unsigned)(unsigned short)s) << 16;
    return x.f;
}
__device__ __forceinline__ short f2b(float f) {  // RNE f32->bf16
    unsigned u = __float_as_uint(f);
    unsigned r = (u + 0x7FFFu + ((u >> 16) & 1u)) >> 16;
    return (short)r;
}
// XOR swizzle on 16B units within a row of the 32x1024 score buffer.
__device__ __forceinline__ int sidx(int r, int c) {
    return (r << 10) + ((((c >> 3) ^ (r & 7)) << 3) | (c & 7));
}

// ---------------- LayerNorm -> bf16 ----------------
__global__ __launch_bounds__(256) void ln_kernel(const float* __restrict__ x,
                                                 const float* __restrict__ g,
                                                 const float* __restrict__ bb,
                                                 short* __restrict__ xnb) {
    int row = blockIdx.x, t = threadIdx.x;
    const float* xr = x + (size_t)row * 768;
    float v0 = xr[t], v1 = xr[t + 256], v2 = xr[t + 512];
    float s = v0 + v1 + v2;
    float ss = v0 * v0 + v1 * v1 + v2 * v2;
#pragma unroll
    for (int o = 1; o < 64; o <<= 1) { s += __shfl_xor(s, o); ss += __shfl_xor(ss, o); }
    __shared__ float red[8];
    int w = t >> 6;
    if ((t & 63) == 0) { red[w] = s; red[4 + w] = ss; }
    __syncthreads();
    s = red[0] + red[1] + red[2] + red[3];
    ss = red[4] + red[5] + red[6] + red[7];
    float mu = s * (1.0f / 768.0f);
    float var = ss * (1.0f / 768.0f) - mu * mu;
    float rs = rsqrtf(var + 1e-5f);
    short* o = xnb + (size_t)row * 768;
    o[t]       = f2b((v0 - mu) * rs * g[t]       + bb[t]);
    o[t + 256] = f2b((v1 - mu) * rs * g[t + 256] + bb[t + 256]);
    o[t + 512] = f2b((v2 - mu) * rs * g[t + 512] + bb[t + 512]);
}

// ---------------- W f32 -> bf16 ----------------
__global__ __launch_bounds__(256) void wconv_kernel(const float* __restrict__ W,
                                                    short* __restrict__ Wb) {
    int i = (blockIdx.x * 256 + threadIdx.x) * 4;
    float4 v = *(const float4*)(W + i);
    short4v o;
    o[0] = f2b(v.x); o[1] = f2b(v.y); o[2] = f2b(v.z); o[3] = f2b(v.w);
    *(short4v*)(Wb + i) = o;
}

// ---------------- QKV GEMM: [4096,768]x[768,2304], bf16 MFMA ----------------
// blockIdx.y 0-5: Q (scaled by 1.2/8), 6-11: K, 12-17: V (transposed to VT via LDS).
__global__ __launch_bounds__(256) void qkv_gemm(const short* __restrict__ A,
                                                const short* __restrict__ B,
                                                const float* __restrict__ bias,
                                                short* __restrict__ Qb,
                                                short* __restrict__ Kb,
                                                short* __restrict__ VT) {
    __shared__ short tile[128][72];  // V-transpose staging (V blocks only)
    int t = threadIdx.x, w = t >> 6, l = t & 63, lr = l & 15, lg = l >> 4;
    int row0 = blockIdx.x * 64 + (w >> 1) * 32;
    int col0 = blockIdx.y * 128 + (w & 1) * 64;
    f32x4 acc[2][4];
#pragma unroll
    for (int rt = 0; rt < 2; ++rt)
#pragma unroll
        for (int ct = 0; ct < 4; ++ct) acc[rt][ct] = (f32x4){0.f, 0.f, 0.f, 0.f};
    for (int k0 = 0; k0 < 768; k0 += 32) {
        short8 a0 = *(const short8*)(A + (row0 + lr) * 768 + k0 + lg * 8);
        short8 a1 = *(const short8*)(A + (row0 + 16 + lr) * 768 + k0 + lg * 8);
#pragma unroll
        for (int ct = 0; ct < 4; ++ct) {
            short8 bf = *(const short8*)(B + (col0 + ct * 16 + lr) * 768 + k0 + lg * 8);
            acc[0][ct] = MFMA16(a0, bf, acc[0][ct]);
            acc[1][ct] = MFMA16(a1, bf, acc[1][ct]);
        }
    }
    int sec = blockIdx.y / 6;  // uniform per block
    if (sec < 2) {
        short* dst = sec ? Kb : Qb;
        const float scl = sec ? 1.0f : (1.2f * 0.125f);
#pragma unroll
        for (int rt = 0; rt < 2; ++rt)
#pragma unroll
            for (int ct = 0; ct < 4; ++ct) {
                int j = col0 + ct * 16 + lr;
                float bs = bias[j];
                int jj = j - sec * 768;
                int h = jj >> 6, d = jj & 63;
#pragma unroll
                for (int i = 0; i < 4; ++i) {
                    int row = row0 + rt * 16 + lg * 4 + i;
                    int b = row >> 10, n = row & 1023;
                    dst[(size_t)(((b * 12 + h) << 10) | n) * 64 + d] = f2b(scl * (acc[rt][ct][i] + bs));
                }
            }
    } else {
        int nbase = (w >> 1) * 32;
#pragma unroll
        for (int rt = 0; rt < 2; ++rt)
#pragma unroll
            for (int ct = 0; ct < 4; ++ct) {
                int j = col0 + ct * 16 + lr;
                float bs = bias[j];
                int jl = (w & 1) * 64 + ct * 16 + lr;
#pragma unroll
                for (int i = 0; i < 4; ++i)
                    tile[jl][nbase + rt * 16 + lg * 4 + i] = f2b(acc[rt][ct][i] + bs);
            }
        __syncthreads();
        int b = blockIdx.x >> 4, n0 = (blockIdx.x & 15) * 64;
        int jl2 = t >> 1, half = t & 1;
        int jj = blockIdx.y * 128 + jl2 - 1536;
        int h = jj >> 6, d = jj & 63;
        short* vtb = VT + (size_t)(b * 12 + h) * 65536;
#pragma unroll
        for (int u = 0; u < 4; ++u) {
            short8 vv = *(short8*)&tile[jl2][half * 32 + u * 8];
            *(short8*)(vtb + d * 1024 + n0 + half * 32 + u * 8) = vv;
        }
    }
}

// ---------------- KK = k[n-1]+k[n]+k[n+1] (zero-padded) ----------------
__global__ __launch_bounds__(256) void kk_kernel(const short* __restrict__ Kb,
                                                 short* __restrict__ KK) {
    int bh = blockIdx.y;
    int t = threadIdx.x;
    int n = blockIdx.x * 32 + (t >> 3), dc = (t & 7) * 8;
    const short* kp = Kb + (size_t)bh * 65536;
    float s[8];
    short8 c = *(const short8*)(kp + n * 64 + dc);
#pragma unroll
    for (int e = 0; e < 8; ++e) s[e] = b2f(c[e]);
    if (n > 0) {
        short8 m = *(const short8*)(kp + (n - 1) * 64 + dc);
#pragma unroll
        for (int e = 0; e < 8; ++e) s[e] += b2f(m[e]);
    }
    if (n < 1023) {
        short8 p = *(const short8*)(kp + (n + 1) * 64 + dc);
#pragma unroll
        for (int e = 0; e < 8; ++e) s[e] += b2f(p[e]);
    }
    short8 o;
#pragma unroll
    for (int e = 0; e < 8; ++e) o[e] = f2b(s[e]);
    *(short8*)(KK + (size_t)bh * 65536 + n * 64 + dc) = o;
}

// ---------------- fused attention: scores->softmax->PV ----------------
// Block: 32 q-rows x 1024 keys, 4 waves. Augmented-K MFMA: ks0-1 from Kb, ks2-3 from KK;
// A-side ks0-1 from (pre-scaled) Qb, ks2-3 from on-the-fly QQ in LDS.
__global__ __launch_bounds__(256) void attn_kernel(const short* __restrict__ Qb,
                                                   const short* __restrict__ Kb,
                                                   const short* __restrict__ KK,
                                                   const short* __restrict__ VT,
                                                   float* __restrict__ out) {
    __shared__ short S[32 * 1024];
    __shared__ short qq[32][72];
    int bh = blockIdx.y, r0 = blockIdx.x * 32;
    int t = threadIdx.x, w = t >> 6, l = t & 63, lr = l & 15, lg = l >> 4;
    const short* qp = Qb + (size_t)bh * 65536;
    const short* kp = Kb + (size_t)bh * 65536;
    const short* kk = KK + (size_t)bh * 65536;
    const short* vt = VT + (size_t)bh * 65536;

    // QQ = -(1/6)*(Qb[n-1]+Qb[n]+Qb[n+1])  (Qb pre-scaled by cq; cs/cq = -1/6)
    {
        int nl = t >> 3, dc = (t & 7) * 8;
        int n = r0 + nl;
        float s[8];
        short8 c = *(const short8*)(qp + n * 64 + dc);
#pragma unroll
        for (int e = 0; e < 8; ++e) s[e] = b2f(c[e]);
        if (n > 0) {
            short8 m = *(const short8*)(qp + (n - 1) * 64 + dc);
#pragma unroll
            for (int e = 0; e < 8; ++e) s[e] += b2f(m[e]);
        }
        if (n < 1023) {
            short8 p = *(const short8*)(qp + (n + 1) * 64 + dc);
#pragma unroll
            for (int e = 0; e < 8; ++e) s[e] += b2f(p[e]);
        }
        short8 o;
#pragma unroll
        for (int e = 0; e < 8; ++e) o[e] = f2b(-(1.0f / 6.0f) * s[e]);
        *(short8*)&qq[nl][dc] = o;
    }
    short8 afr[2][4];
#pragma unroll
    for (int rt = 0; rt < 2; ++rt)
#pragma unroll
        for (int ks = 0; ks < 2; ++ks)
            afr[rt][ks] = *(const short8*)(qp + (r0 + rt * 16 + lr) * 64 + ks * 32 + lg * 8);
    __syncthreads();
#pragma unroll
    for (int rt = 0; rt < 2; ++rt)
#pragma unroll
        for (int ks = 2; ks < 4; ++ks)
            afr[rt][ks] = *(const short8*)&qq[rt * 16 + lr][(ks - 2) * 32 + lg * 8];

    // Phase 1: scores, each wave owns 16 col-tiles x both row-tiles.
    for (int ct = 0; ct < 16; ++ct) {
        int m0 = (w * 16 + ct) * 16;
        short8 bfr[4];
#pragma unroll
        for (int ks = 0; ks < 2; ++ks)
            bfr[ks] = *(const short8*)(kp + (m0 + lr) * 64 + ks * 32 + lg * 8);
#pragma unroll
        for (int ks = 2; ks < 4; ++ks)
            bfr[ks] = *(const short8*)(kk + (m0 + lr) * 64 + (ks - 2) * 32 + lg * 8);
        f32x4 a0 = (f32x4){0.f, 0.f, 0.f, 0.f};
        f32x4 a1 = (f32x4){0.f, 0.f, 0.f, 0.f};
#pragma unroll
        for (int ks = 0; ks < 4; ++ks) {
            a0 = MFMA16(afr[0][ks], bfr[ks], a0);
            a1 = MFMA16(afr[1][ks], bfr[ks], a1);
        }
        int c = m0 + lr;
#pragma unroll
        for (int i = 0; i < 4; ++i) {
            S[sidx(lg * 4 + i, c)]      = f2b(a0[i]);
            S[sidx(16 + lg * 4 + i, c)] = f2b(a1[i]);
        }
    }
    __syncthreads();

    // Phase 2: in-place row softmax.
    for (int r = w * 8; r < w * 8 + 8; ++r) {
        short8 c0 = *(short8*)&S[sidx(r, l * 8)];
        short8 c1 = *(short8*)&S[sidx(r, 512 + l * 8)];
        float v[16];
#pragma unroll
        for (int e = 0; e < 8; ++e) { v[e] = b2f(c0[e]); v[8 + e] = b2f(c1[e]); }
        float mx = v[0];
#pragma unroll
        for (int e = 1; e < 16; ++e) mx = fmaxf(mx, v[e]);
#pragma unroll
        for (int o = 1; o < 64; o <<= 1) mx = fmaxf(mx, __shfl_xor(mx, o));
        float sm = 0.f;
#pragma unroll
        for (int e = 0; e < 16; ++e) { v[e] = __expf(v[e] - mx); sm += v[e]; }
#pragma unroll
        for (int o = 1; o < 64; o <<= 1) sm += __shfl_xor(sm, o);
        float inv = 1.f / sm;
#pragma unroll
        for (int e = 0; e < 8; ++e) { c0[e] = f2b(v[e] * inv); c1[e] = f2b(v[8 + e] * inv); }
        *(short8*)&S[sidx(r, l * 8)] = c0;
        *(short8*)&S[sidx(r, 512 + l * 8)] = c1;
    }
    __syncthreads();

    // Phase 3: PV (K=1024), wave w owns output cols d0..d0+15.
    int d0 = w * 16;
    f32x4 acc[2];
    acc[0] = (f32x4){0.f, 0.f, 0.f, 0.f};
    acc[1] = (f32x4){0.f, 0.f, 0.f, 0.f};
    for (int ks = 0; ks < 32; ++ks) {
        short8 bfr = *(const short8*)(vt + (d0 + lr) * 1024 + ks * 32 + lg * 8);
#pragma unroll
        for (int rt = 0; rt < 2; ++rt) {
            short8 af = *(const short8*)&S[sidx(rt * 16 + lr, ks * 32 + lg * 8)];
            acc[rt] = MFMA16(af, bfr, acc[rt]);
        }
    }
    int b = bh / 12, h = bh - b * 12;
#pragma unroll
    for (int rt = 0; rt < 2; ++rt)
#pragma unroll
        for (int i = 0; i < 4; ++i) {
            int n = r0 + rt * 16 + lg * 4 + i;
            out[(size_t)(b * 1024 + n) * 768 + h * 64 + d0 + lr] = acc[rt][i];
        }
}

extern "C" void kernel_launch(void* const* d_in, const int* in_sizes, int n_in,
                              void* d_out, int out_size, void* d_ws, size_t ws_size,
                              hipStream_t stream) {
    const float* x  = (const float*)d_in[0];
    const float* W  = (const float*)d_in[1];
    const float* qb = (const float*)d_in[2];
    const float* lg = (const float*)d_in[3];
    const float* lb = (const float*)d_in[4];
    float* out = (float*)d_out;
    char* ws = (char*)d_ws;
    // Workspace layout (peak 28,704,768 bytes):
    short* xnb = (short*)(ws + 0);         // [4096][768] bf16 (dead after gemm)
    short* Wb  = (short*)(ws + 6291456);   // [2304][768] bf16
    short* Qb  = (short*)(ws + 9830400);   // [48][1024][64] bf16, pre-scaled by 1.2/8
    short* Kb  = (short*)(ws + 16121856);  // [48][1024][64] bf16
    short* VT  = (short*)(ws + 22413312);  // [48][64][1024] bf16
    short* KK  = (short*)(ws + 0);         // [48][1024][64] bf16, overlays dead xnb

    hipLaunchKernelGGL(ln_kernel, dim3(4096), dim3(256), 0, stream, x, lg, lb, xnb);
    hipLaunchKernelGGL(wconv_kernel, dim3(1728), dim3(256), 0, stream, W, Wb);
    hipLaunchKernelGGL(qkv_gemm, dim3(64, 18), dim3(256), 0, stream, xnb, Wb, qb, Qb, Kb, VT);
    hipLaunchKernelGGL(kk_kernel, dim3(32, 48), dim3(256), 0, stream, Kb, KK);
    hipLaunchKernelGGL(attn_kernel, dim3(32, 48), dim3(256), 0, stream, Qb, Kb, KK, VT, out);
}

// Round 3
// 144.627 us; speedup vs baseline: 1.3676x; 1.3676x over previous
//
#include <hip/hip_runtime.h>

// LateralInhibitionAttention, MI355X.
// Conv3x3 of the rank-structured score matrix factorizes:
//   sum_{3x3} s[n+i][m+j] = (q[n-1]+q[n]+q[n+1]) . (k[m-1]+k[m]+k[m+1])
// so inhibited scores = [cq*q ; cs*qsum] . [k ; ksum]  (augmented 128-dim dot)
// with cq = 1.2*D^-0.5, cs = -0.2*D^-0.5 -> plain softmax attention.
// R2: qkv_gemm was latency-bound (MfmaUtil 5%, 100us) -> m97-structure LDS-staged
// GEMM with global_load_lds width=16, 128x128 tile, BK=32.

using short8 = __attribute__((ext_vector_type(8))) short;
using short4v = __attribute__((ext_vector_type(4))) short;
using f32x4 = __attribute__((ext_vector_type(4))) float;

#define MFMA16(a, b, c) __builtin_amdgcn_mfma_f32_16x16x32_bf16((a), (b), (c), 0, 0, 0)

__device__ __forceinline__ float b2f(short s) {
    union { unsigned u; float f; } x;
    x.u = ((unsigned)(unsigned short)s) << 16;
    return x.f;
}
__device__ __forceinline__ short f2b(float f) {  // RNE f32->bf16
    unsigned u = __float_as_uint(f);
    unsigned r = (u + 0x7FFFu + ((u >> 16) & 1u)) >> 16;
    return (short)r;
}
// XOR swizzle on 16B units within a row of the 32x1024 score buffer.
__device__ __forceinline__ int sidx(int r, int c) {
    return (r << 10) + ((((c >> 3) ^ (r & 7)) << 3) | (c & 7));
}
// async global->LDS, 16B per lane; lds dest must be wave-uniform base (+lane*16 implicit)
__device__ __forceinline__ void gload_lds16(const short* g, short* l) {
    __builtin_amdgcn_global_load_lds(
        (const __attribute__((address_space(1))) void*)g,
        (__attribute__((address_space(3))) void*)l, 16, 0, 0);
}

// ---------------- LayerNorm -> bf16 ----------------
__global__ __launch_bounds__(256) void ln_kernel(const float* __restrict__ x,
                                                 const float* __restrict__ g,
                                                 const float* __restrict__ bb,
                                                 short* __restrict__ xnb) {
    int row = blockIdx.x, t = threadIdx.x;
    const float* xr = x + (size_t)row * 768;
    float v0 = xr[t], v1 = xr[t + 256], v2 = xr[t + 512];
    float s = v0 + v1 + v2;
    float ss = v0 * v0 + v1 * v1 + v2 * v2;
#pragma unroll
    for (int o = 1; o < 64; o <<= 1) { s += __shfl_xor(s, o); ss += __shfl_xor(ss, o); }
    __shared__ float red[8];
    int w = t >> 6;
    if ((t & 63) == 0) { red[w] = s; red[4 + w] = ss; }
    __syncthreads();
    s = red[0] + red[1] + red[2] + red[3];
    ss = red[4] + red[5] + red[6] + red[7];
    float mu = s * (1.0f / 768.0f);
    float var = ss * (1.0f / 768.0f) - mu * mu;
    float rs = rsqrtf(var + 1e-5f);
    short* o = xnb + (size_t)row * 768;
    o[t]       = f2b((v0 - mu) * rs * g[t]       + bb[t]);
    o[t + 256] = f2b((v1 - mu) * rs * g[t + 256] + bb[t + 256]);
    o[t + 512] = f2b((v2 - mu) * rs * g[t + 512] + bb[t + 512]);
}

// ---------------- W f32 -> bf16 ----------------
__global__ __launch_bounds__(256) void wconv_kernel(const float* __restrict__ W,
                                                    short* __restrict__ Wb) {
    int i = (blockIdx.x * 256 + threadIdx.x) * 4;
    float4 v = *(const float4*)(W + i);
    short4v o;
    o[0] = f2b(v.x); o[1] = f2b(v.y); o[2] = f2b(v.z); o[3] = f2b(v.w);
    *(short4v*)(Wb + i) = o;
}

// ---------------- QKV GEMM: [4096,768]x[768,2304]^T, m97-structure ----------------
// 128x128 tile, BK=32, 4 waves 2x2, global_load_lds staging.
// blockIdx.y 0-5: Q (scaled by 1.2/8), 6-11: K, 12-17: V (transposed to VT via LDS).
__global__ __launch_bounds__(256) void qkv_gemm(const short* __restrict__ A,
                                                const short* __restrict__ B,
                                                const float* __restrict__ bias,
                                                short* __restrict__ Qb,
                                                short* __restrict__ Kb,
                                                short* __restrict__ VT) {
    __shared__ char smem[17408];
    short* As = (short*)smem;            // [128][32] bf16
    short* Bs = (short*)(smem + 8192);   // [128][32] bf16
    int t = threadIdx.x, w = t >> 6, l = t & 63, lr = l & 15, lg = l >> 4;
    int wr = w >> 1, wc = w & 1;
    int row0 = blockIdx.x * 128;
    int col0 = blockIdx.y * 128;
    // staging: chunk c (=t, t+256) -> row c>>2, 8-col group c&3; LDS linear in lane order
    const short* agp0 = A + (size_t)(row0 + (t >> 2)) * 768 + (t & 3) * 8;
    const short* agp1 = agp0 + (size_t)64 * 768;
    const short* bgp0 = B + (size_t)(col0 + (t >> 2)) * 768 + (t & 3) * 8;
    const short* bgp1 = bgp0 + (size_t)64 * 768;
    short* asl0 = As + (w * 64) * 8;
    short* asl1 = As + (256 + w * 64) * 8;
    short* bsl0 = Bs + (w * 64) * 8;
    short* bsl1 = Bs + (256 + w * 64) * 8;

    f32x4 acc[4][4];
#pragma unroll
    for (int m = 0; m < 4; ++m)
#pragma unroll
        for (int n = 0; n < 4; ++n) acc[m][n] = (f32x4){0.f, 0.f, 0.f, 0.f};

    for (int k0 = 0; k0 < 768; k0 += 32) {
        gload_lds16(agp0 + k0, asl0);
        gload_lds16(agp1 + k0, asl1);
        gload_lds16(bgp0 + k0, bsl0);
        gload_lds16(bgp1 + k0, bsl1);
        __syncthreads();
        short8 af[4], bf[4];
#pragma unroll
        for (int m = 0; m < 4; ++m)
            af[m] = *(short8*)&As[(wr * 64 + m * 16 + lr) * 32 + lg * 8];
#pragma unroll
        for (int n = 0; n < 4; ++n)
            bf[n] = *(short8*)&Bs[(wc * 64 + n * 16 + lr) * 32 + lg * 8];
#pragma unroll
        for (int m = 0; m < 4; ++m)
#pragma unroll
            for (int n = 0; n < 4; ++n)
                acc[m][n] = MFMA16(af[m], bf[n], acc[m][n]);
        __syncthreads();
    }

    int sec = blockIdx.y / 6;  // uniform per block
    if (sec < 2) {
        short* dst = sec ? Kb : Qb;
        const float scl = sec ? 1.0f : (1.2f * 0.125f);
#pragma unroll
        for (int n = 0; n < 4; ++n) {
            int j = col0 + wc * 64 + n * 16 + lr;
            float bs = bias[j];
            int jj = j - sec * 768;
            int h = jj >> 6, d = jj & 63;
#pragma unroll
            for (int m = 0; m < 4; ++m)
#pragma unroll
                for (int i = 0; i < 4; ++i) {
                    int row = row0 + wr * 64 + m * 16 + lg * 4 + i;
                    int b = row >> 10, n_ = row & 1023;
                    dst[(size_t)(((b * 12 + h) << 10) | n_) * 64 + d] =
                        f2b(scl * (acc[m][n][i] + bs));
                }
        }
    } else {
        // V: transpose 128x128 tile -> VT[d][n], two 64-col passes through LDS
        short* tr = (short*)smem;  // [64][136]
        int b = row0 >> 10, nin = row0 & 1023;
        int jj0 = col0 - 1536;
        for (int p = 0; p < 2; ++p) {
            __syncthreads();
            if (wc == p) {
#pragma unroll
                for (int n = 0; n < 4; ++n) {
                    int jl = n * 16 + lr;
                    float bs = bias[col0 + p * 64 + jl];
#pragma unroll
                    for (int m = 0; m < 4; ++m) {
                        int nl = wr * 64 + m * 16 + lg * 4;
                        short4v o;
#pragma unroll
                        for (int i = 0; i < 4; ++i) o[i] = f2b(acc[m][n][i] + bs);
                        *(short4v*)&tr[jl * 136 + nl] = o;
                    }
                }
            }
            __syncthreads();
            int jl = t >> 2, qd = t & 3;
            int j = jj0 + p * 64 + jl;
            int h = j >> 6, d = j & 63;
            short* vtb = VT + (size_t)(b * 12 + h) * 65536 + d * 1024 + nin + qd * 32;
#pragma unroll
            for (int u = 0; u < 4; ++u)
                *(short8*)(vtb + u * 8) = *(short8*)&tr[jl * 136 + qd * 32 + u * 8];
        }
    }
}

// ---------------- KK = k[n-1]+k[n]+k[n+1] (zero-padded) ----------------
__global__ __launch_bounds__(256) void kk_kernel(const short* __restrict__ Kb,
                                                 short* __restrict__ KK) {
    int bh = blockIdx.y;
    int t = threadIdx.x;
    int n = blockIdx.x * 32 + (t >> 3), dc = (t & 7) * 8;
    const short* kp = Kb + (size_t)bh * 65536;
    float s[8];
    short8 c = *(const short8*)(kp + n * 64 + dc);
#pragma unroll
    for (int e = 0; e < 8; ++e) s[e] = b2f(c[e]);
    if (n > 0) {
        short8 m = *(const short8*)(kp + (n - 1) * 64 + dc);
#pragma unroll
        for (int e = 0; e < 8; ++e) s[e] += b2f(m[e]);
    }
    if (n < 1023) {
        short8 p = *(const short8*)(kp + (n + 1) * 64 + dc);
#pragma unroll
        for (int e = 0; e < 8; ++e) s[e] += b2f(p[e]);
    }
    short8 o;
#pragma unroll
    for (int e = 0; e < 8; ++e) o[e] = f2b(s[e]);
    *(short8*)(KK + (size_t)bh * 65536 + n * 64 + dc) = o;
}

// ---------------- fused attention: scores->softmax->PV ----------------
// Block: 32 q-rows x 1024 keys, 4 waves. Augmented-K MFMA: ks0-1 from Kb, ks2-3 from KK;
// A-side ks0-1 from (pre-scaled) Qb, ks2-3 from on-the-fly QQ in LDS.
__global__ __launch_bounds__(256) void attn_kernel(const short* __restrict__ Qb,
                                                   const short* __restrict__ Kb,
                                                   const short* __restrict__ KK,
                                                   const short* __restrict__ VT,
                                                   float* __restrict__ out) {
    __shared__ short S[32 * 1024];
    __shared__ short qq[32][72];
    int bh = blockIdx.y, r0 = blockIdx.x * 32;
    int t = threadIdx.x, w = t >> 6, l = t & 63, lr = l & 15, lg = l >> 4;
    const short* qp = Qb + (size_t)bh * 65536;
    const short* kp = Kb + (size_t)bh * 65536;
    const short* kk = KK + (size_t)bh * 65536;
    const short* vt = VT + (size_t)bh * 65536;

    // QQ = -(1/6)*(Qb[n-1]+Qb[n]+Qb[n+1])  (Qb pre-scaled by cq; cs/cq = -1/6)
    {
        int nl = t >> 3, dc = (t & 7) * 8;
        int n = r0 + nl;
        float s[8];
        short8 c = *(const short8*)(qp + n * 64 + dc);
#pragma unroll
        for (int e = 0; e < 8; ++e) s[e] = b2f(c[e]);
        if (n > 0) {
            short8 m = *(const short8*)(qp + (n - 1) * 64 + dc);
#pragma unroll
            for (int e = 0; e < 8; ++e) s[e] += b2f(m[e]);
        }
        if (n < 1023) {
            short8 p = *(const short8*)(qp + (n + 1) * 64 + dc);
#pragma unroll
            for (int e = 0; e < 8; ++e) s[e] += b2f(p[e]);
        }
        short8 o;
#pragma unroll
        for (int e = 0; e < 8; ++e) o[e] = f2b(-(1.0f / 6.0f) * s[e]);
        *(short8*)&qq[nl][dc] = o;
    }
    short8 afr[2][4];
#pragma unroll
    for (int rt = 0; rt < 2; ++rt)
#pragma unroll
        for (int ks = 0; ks < 2; ++ks)
            afr[rt][ks] = *(const short8*)(qp + (r0 + rt * 16 + lr) * 64 + ks * 32 + lg * 8);
    __syncthreads();
#pragma unroll
    for (int rt = 0; rt < 2; ++rt)
#pragma unroll
        for (int ks = 2; ks < 4; ++ks)
            afr[rt][ks] = *(const short8*)&qq[rt * 16 + lr][(ks - 2) * 32 + lg * 8];

    // Phase 1: scores, each wave owns 16 col-tiles x both row-tiles.
    for (int ct = 0; ct < 16; ++ct) {
        int m0 = (w * 16 + ct) * 16;
        short8 bfr[4];
#pragma unroll
        for (int ks = 0; ks < 2; ++ks)
            bfr[ks] = *(const short8*)(kp + (m0 + lr) * 64 + ks * 32 + lg * 8);
#pragma unroll
        for (int ks = 2; ks < 4; ++ks)
            bfr[ks] = *(const short8*)(kk + (m0 + lr) * 64 + (ks - 2) * 32 + lg * 8);
        f32x4 a0 = (f32x4){0.f, 0.f, 0.f, 0.f};
        f32x4 a1 = (f32x4){0.f, 0.f, 0.f, 0.f};
#pragma unroll
        for (int ks = 0; ks < 4; ++ks) {
            a0 = MFMA16(afr[0][ks], bfr[ks], a0);
            a1 = MFMA16(afr[1][ks], bfr[ks], a1);
        }
        int c = m0 + lr;
#pragma unroll
        for (int i = 0; i < 4; ++i) {
            S[sidx(lg * 4 + i, c)]      = f2b(a0[i]);
            S[sidx(16 + lg * 4 + i, c)] = f2b(a1[i]);
        }
    }
    __syncthreads();

    // Phase 2: in-place row softmax.
    for (int r = w * 8; r < w * 8 + 8; ++r) {
        short8 c0 = *(short8*)&S[sidx(r, l * 8)];
        short8 c1 = *(short8*)&S[sidx(r, 512 + l * 8)];
        float v[16];
#pragma unroll
        for (int e = 0; e < 8; ++e) { v[e] = b2f(c0[e]); v[8 + e] = b2f(c1[e]); }
        float mx = v[0];
#pragma unroll
        for (int e = 1; e < 16; ++e) mx = fmaxf(mx, v[e]);
#pragma unroll
        for (int o = 1; o < 64; o <<= 1) mx = fmaxf(mx, __shfl_xor(mx, o));
        float sm = 0.f;
#pragma unroll
        for (int e = 0; e < 16; ++e) { v[e] = __expf(v[e] - mx); sm += v[e]; }
#pragma unroll
        for (int o = 1; o < 64; o <<= 1) sm += __shfl_xor(sm, o);
        float inv = 1.f / sm;
#pragma unroll
        for (int e = 0; e < 8; ++e) { c0[e] = f2b(v[e] * inv); c1[e] = f2b(v[8 + e] * inv); }
        *(short8*)&S[sidx(r, l * 8)] = c0;
        *(short8*)&S[sidx(r, 512 + l * 8)] = c1;
    }
    __syncthreads();

    // Phase 3: PV (K=1024), wave w owns output cols d0..d0+15.
    int d0 = w * 16;
    f32x4 acc[2];
    acc[0] = (f32x4){0.f, 0.f, 0.f, 0.f};
    acc[1] = (f32x4){0.f, 0.f, 0.f, 0.f};
    for (int ks = 0; ks < 32; ++ks) {
        short8 bfr = *(const short8*)(vt + (d0 + lr) * 1024 + ks * 32 + lg * 8);
#pragma unroll
        for (int rt = 0; rt < 2; ++rt) {
            short8 af = *(const short8*)&S[sidx(rt * 16 + lr, ks * 32 + lg * 8)];
            acc[rt] = MFMA16(af, bfr, acc[rt]);
        }
    }
    int b = bh / 12, h = bh - b * 12;
#pragma unroll
    for (int rt = 0; rt < 2; ++rt)
#pragma unroll
        for (int i = 0; i < 4; ++i) {
            int n = r0 + rt * 16 + lg * 4 + i;
            out[(size_t)(b * 1024 + n) * 768 + h * 64 + d0 + lr] = acc[rt][i];
        }
}

extern "C" void kernel_launch(void* const* d_in, const int* in_sizes, int n_in,
                              void* d_out, int out_size, void* d_ws, size_t ws_size,
                              hipStream_t stream) {
    const float* x  = (const float*)d_in[0];
    const float* W  = (const float*)d_in[1];
    const float* qb = (const float*)d_in[2];
    const float* lg = (const float*)d_in[3];
    const float* lb = (const float*)d_in[4];
    float* out = (float*)d_out;
    char* ws = (char*)d_ws;
    // Workspace layout (peak 28,704,768 bytes):
    short* xnb = (short*)(ws + 0);         // [4096][768] bf16 (dead after gemm)
    short* Wb  = (short*)(ws + 6291456);   // [2304][768] bf16
    short* Qb  = (short*)(ws + 9830400);   // [48][1024][64] bf16, pre-scaled by 1.2/8
    short* Kb  = (short*)(ws + 16121856);  // [48][1024][64] bf16
    short* VT  = (short*)(ws + 22413312);  // [48][64][1024] bf16
    short* KK  = (short*)(ws + 0);         // [48][1024][64] bf16, overlays dead xnb

    hipLaunchKernelGGL(ln_kernel, dim3(4096), dim3(256), 0, stream, x, lg, lb, xnb);
    hipLaunchKernelGGL(wconv_kernel, dim3(1728), dim3(256), 0, stream, W, Wb);
    hipLaunchKernelGGL(qkv_gemm, dim3(32, 18), dim3(256), 0, stream, xnb, Wb, qb, Qb, Kb, VT);
    hipLaunchKernelGGL(kk_kernel, dim3(32, 48), dim3(256), 0, stream, Kb, KK);
    hipLaunchKernelGGL(attn_kernel, dim3(32, 48), dim3(256), 0, stream, Qb, Kb, KK, VT, out);
}

// Round 4
// 139.174 us; speedup vs baseline: 1.4211x; 1.0392x over previous
//
#include <hip/hip_runtime.h>

// LateralInhibitionAttention, MI355X.
// Conv3x3 of the rank-structured score matrix factorizes:
//   sum_{3x3} s[n+i][m+j] = (q[n-1]+q[n]+q[n+1]) . (k[m-1]+k[m]+k[m+1])
// so inhibited scores = [cq*q ; cs*qsum] . [k ; ksum]  (augmented 128-dim dot)
// with cq = 1.2*D^-0.5, cs = -0.2*D^-0.5 -> plain softmax attention.
// R3: attn_kernel latency-bound (MfmaUtil 7.7%, FETCH 77MB vs 19MB working set).
//   -> XCD-affinity swizzle (all 32 q-tiles of a head on one XCD's L2),
//      register ping-pong prefetch of K/KK/VT fragments, S-swizzle mask 7->15.

using short8 = __attribute__((ext_vector_type(8))) short;
using short4v = __attribute__((ext_vector_type(4))) short;
using f32x4 = __attribute__((ext_vector_type(4))) float;

#define MFMA16(a, b, c) __builtin_amdgcn_mfma_f32_16x16x32_bf16((a), (b), (c), 0, 0, 0)

__device__ __forceinline__ float b2f(short s) {
    union { unsigned u; float f; } x;
    x.u = ((unsigned)(unsigned short)s) << 16;
    return x.f;
}
__device__ __forceinline__ short f2b(float f) {  // RNE f32->bf16
    unsigned u = __float_as_uint(f);
    unsigned r = (u + 0x7FFFu + ((u >> 16) & 1u)) >> 16;
    return (short)r;
}
// XOR swizzle on 16B units within a row of the 32x1024 score buffer (mask 15:
// phase-1 scalar stores land 2-way/bank = free; phase-2 reads 2-way).
__device__ __forceinline__ int sidx(int r, int c) {
    return (r << 10) + ((((c >> 3) ^ (r & 15)) << 3) | (c & 7));
}
// async global->LDS, 16B per lane; lds dest must be wave-uniform base (+lane*16 implicit)
__device__ __forceinline__ void gload_lds16(const short* g, short* l) {
    __builtin_amdgcn_global_load_lds(
        (const __attribute__((address_space(1))) void*)g,
        (__attribute__((address_space(3))) void*)l, 16, 0, 0);
}

// ---------------- LayerNorm -> bf16 ----------------
__global__ __launch_bounds__(256) void ln_kernel(const float* __restrict__ x,
                                                 const float* __restrict__ g,
                                                 const float* __restrict__ bb,
                                                 short* __restrict__ xnb) {
    int row = blockIdx.x, t = threadIdx.x;
    const float* xr = x + (size_t)row * 768;
    float v0 = xr[t], v1 = xr[t + 256], v2 = xr[t + 512];
    float s = v0 + v1 + v2;
    float ss = v0 * v0 + v1 * v1 + v2 * v2;
#pragma unroll
    for (int o = 1; o < 64; o <<= 1) { s += __shfl_xor(s, o); ss += __shfl_xor(ss, o); }
    __shared__ float red[8];
    int w = t >> 6;
    if ((t & 63) == 0) { red[w] = s; red[4 + w] = ss; }
    __syncthreads();
    s = red[0] + red[1] + red[2] + red[3];
    ss = red[4] + red[5] + red[6] + red[7];
    float mu = s * (1.0f / 768.0f);
    float var = ss * (1.0f / 768.0f) - mu * mu;
    float rs = rsqrtf(var + 1e-5f);
    short* o = xnb + (size_t)row * 768;
    o[t]       = f2b((v0 - mu) * rs * g[t]       + bb[t]);
    o[t + 256] = f2b((v1 - mu) * rs * g[t + 256] + bb[t + 256]);
    o[t + 512] = f2b((v2 - mu) * rs * g[t + 512] + bb[t + 512]);
}

// ---------------- W f32 -> bf16 ----------------
__global__ __launch_bounds__(256) void wconv_kernel(const float* __restrict__ W,
                                                    short* __restrict__ Wb) {
    int i = (blockIdx.x * 256 + threadIdx.x) * 4;
    float4 v = *(const float4*)(W + i);
    short4v o;
    o[0] = f2b(v.x); o[1] = f2b(v.y); o[2] = f2b(v.z); o[3] = f2b(v.w);
    *(short4v*)(Wb + i) = o;
}

// ---------------- QKV GEMM: [4096,768]x[768,2304]^T, m97-structure ----------------
// 128x128 tile, BK=32, 4 waves 2x2, global_load_lds staging.
// blockIdx.y 0-5: Q (scaled by 1.2/8), 6-11: K, 12-17: V (transposed to VT via LDS).
__global__ __launch_bounds__(256) void qkv_gemm(const short* __restrict__ A,
                                                const short* __restrict__ B,
                                                const float* __restrict__ bias,
                                                short* __restrict__ Qb,
                                                short* __restrict__ Kb,
                                                short* __restrict__ VT) {
    __shared__ char smem[17408];
    short* As = (short*)smem;            // [128][32] bf16
    short* Bs = (short*)(smem + 8192);   // [128][32] bf16
    int t = threadIdx.x, w = t >> 6, l = t & 63, lr = l & 15, lg = l >> 4;
    int wr = w >> 1, wc = w & 1;
    int row0 = blockIdx.x * 128;
    int col0 = blockIdx.y * 128;
    // staging: chunk c (=t, t+256) -> row c>>2, 8-col group c&3; LDS linear in lane order
    const short* agp0 = A + (size_t)(row0 + (t >> 2)) * 768 + (t & 3) * 8;
    const short* agp1 = agp0 + (size_t)64 * 768;
    const short* bgp0 = B + (size_t)(col0 + (t >> 2)) * 768 + (t & 3) * 8;
    const short* bgp1 = bgp0 + (size_t)64 * 768;
    short* asl0 = As + (w * 64) * 8;
    short* asl1 = As + (256 + w * 64) * 8;
    short* bsl0 = Bs + (w * 64) * 8;
    short* bsl1 = Bs + (256 + w * 64) * 8;

    f32x4 acc[4][4];
#pragma unroll
    for (int m = 0; m < 4; ++m)
#pragma unroll
        for (int n = 0; n < 4; ++n) acc[m][n] = (f32x4){0.f, 0.f, 0.f, 0.f};

    for (int k0 = 0; k0 < 768; k0 += 32) {
        gload_lds16(agp0 + k0, asl0);
        gload_lds16(agp1 + k0, asl1);
        gload_lds16(bgp0 + k0, bsl0);
        gload_lds16(bgp1 + k0, bsl1);
        __syncthreads();
        short8 af[4], bf[4];
#pragma unroll
        for (int m = 0; m < 4; ++m)
            af[m] = *(short8*)&As[(wr * 64 + m * 16 + lr) * 32 + lg * 8];
#pragma unroll
        for (int n = 0; n < 4; ++n)
            bf[n] = *(short8*)&Bs[(wc * 64 + n * 16 + lr) * 32 + lg * 8];
#pragma unroll
        for (int m = 0; m < 4; ++m)
#pragma unroll
            for (int n = 0; n < 4; ++n)
                acc[m][n] = MFMA16(af[m], bf[n], acc[m][n]);
        __syncthreads();
    }

    int sec = blockIdx.y / 6;  // uniform per block
    if (sec < 2) {
        short* dst = sec ? Kb : Qb;
        const float scl = sec ? 1.0f : (1.2f * 0.125f);
#pragma unroll
        for (int n = 0; n < 4; ++n) {
            int j = col0 + wc * 64 + n * 16 + lr;
            float bs = bias[j];
            int jj = j - sec * 768;
            int h = jj >> 6, d = jj & 63;
#pragma unroll
            for (int m = 0; m < 4; ++m)
#pragma unroll
                for (int i = 0; i < 4; ++i) {
                    int row = row0 + wr * 64 + m * 16 + lg * 4 + i;
                    int b = row >> 10, n_ = row & 1023;
                    dst[(size_t)(((b * 12 + h) << 10) | n_) * 64 + d] =
                        f2b(scl * (acc[m][n][i] + bs));
                }
        }
    } else {
        // V: transpose 128x128 tile -> VT[d][n], two 64-col passes through LDS
        short* tr = (short*)smem;  // [64][136]
        int b = row0 >> 10, nin = row0 & 1023;
        int jj0 = col0 - 1536;
        for (int p = 0; p < 2; ++p) {
            __syncthreads();
            if (wc == p) {
#pragma unroll
                for (int n = 0; n < 4; ++n) {
                    int jl = n * 16 + lr;
                    float bs = bias[col0 + p * 64 + jl];
#pragma unroll
                    for (int m = 0; m < 4; ++m) {
                        int nl = wr * 64 + m * 16 + lg * 4;
                        short4v o;
#pragma unroll
                        for (int i = 0; i < 4; ++i) o[i] = f2b(acc[m][n][i] + bs);
                        *(short4v*)&tr[jl * 136 + nl] = o;
                    }
                }
            }
            __syncthreads();
            int jl = t >> 2, qd = t & 3;
            int j = jj0 + p * 64 + jl;
            int h = j >> 6, d = j & 63;
            short* vtb = VT + (size_t)(b * 12 + h) * 65536 + d * 1024 + nin + qd * 32;
#pragma unroll
            for (int u = 0; u < 4; ++u)
                *(short8*)(vtb + u * 8) = *(short8*)&tr[jl * 136 + qd * 32 + u * 8];
        }
    }
}

// ---------------- KK = k[n-1]+k[n]+k[n+1] (zero-padded) ----------------
__global__ __launch_bounds__(256) void kk_kernel(const short* __restrict__ Kb,
                                                 short* __restrict__ KK) {
    int bh = blockIdx.y;
    int t = threadIdx.x;
    int n = blockIdx.x * 32 + (t >> 3), dc = (t & 7) * 8;
    const short* kp = Kb + (size_t)bh * 65536;
    float s[8];
    short8 c = *(const short8*)(kp + n * 64 + dc);
#pragma unroll
    for (int e = 0; e < 8; ++e) s[e] = b2f(c[e]);
    if (n > 0) {
        short8 m = *(const short8*)(kp + (n - 1) * 64 + dc);
#pragma unroll
        for (int e = 0; e < 8; ++e) s[e] += b2f(m[e]);
    }
    if (n < 1023) {
        short8 p = *(const short8*)(kp + (n + 1) * 64 + dc);
#pragma unroll
        for (int e = 0; e < 8; ++e) s[e] += b2f(p[e]);
    }
    short8 o;
#pragma unroll
    for (int e = 0; e < 8; ++e) o[e] = f2b(s[e]);
    *(short8*)(KK + (size_t)bh * 65536 + n * 64 + dc) = o;
}

// ---------------- fused attention: scores->softmax->PV ----------------
// Flat grid 1536, decoded so all 32 q-tile blocks of a head share one XCD
// (default dispatch: consecutive blocks round-robin XCDs; head = hi*8 + (d&7)).
// Augmented-K MFMA: ks0-1 from Kb, ks2-3 from KK; A-side ks2-3 from on-the-fly QQ.
__global__ __launch_bounds__(256) void attn_kernel(const short* __restrict__ Qb,
                                                   const short* __restrict__ Kb,
                                                   const short* __restrict__ KK,
                                                   const short* __restrict__ VT,
                                                   float* __restrict__ out) {
    __shared__ short S[32 * 1024];
    __shared__ short qq[32][72];
    int d = blockIdx.x;
    int xcd = d & 7, rr = d >> 3;
    int r0 = (rr & 31) * 32;
    int bh = (rr >> 5) * 8 + xcd;
    int t = threadIdx.x, w = t >> 6, l = t & 63, lr = l & 15, lg = l >> 4;
    const short* qp = Qb + (size_t)bh * 65536;
    const short* kp = Kb + (size_t)bh * 65536;
    const short* kk = KK + (size_t)bh * 65536;
    const short* vt = VT + (size_t)bh * 65536;

    // QQ = -(1/6)*(Qb[n-1]+Qb[n]+Qb[n+1])  (Qb pre-scaled by cq; cs/cq = -1/6)
    {
        int nl = t >> 3, dc = (t & 7) * 8;
        int n = r0 + nl;
        float s[8];
        short8 c = *(const short8*)(qp + n * 64 + dc);
#pragma unroll
        for (int e = 0; e < 8; ++e) s[e] = b2f(c[e]);
        if (n > 0) {
            short8 m = *(const short8*)(qp + (n - 1) * 64 + dc);
#pragma unroll
            for (int e = 0; e < 8; ++e) s[e] += b2f(m[e]);
        }
        if (n < 1023) {
            short8 p = *(const short8*)(qp + (n + 1) * 64 + dc);
#pragma unroll
            for (int e = 0; e < 8; ++e) s[e] += b2f(p[e]);
        }
        short8 o;
#pragma unroll
        for (int e = 0; e < 8; ++e) o[e] = f2b(-(1.0f / 6.0f) * s[e]);
        *(short8*)&qq[nl][dc] = o;
    }
    short8 afr[2][4];
#pragma unroll
    for (int rt = 0; rt < 2; ++rt)
#pragma unroll
        for (int ks = 0; ks < 2; ++ks)
            afr[rt][ks] = *(const short8*)(qp + (r0 + rt * 16 + lr) * 64 + ks * 32 + lg * 8);
    __syncthreads();
#pragma unroll
    for (int rt = 0; rt < 2; ++rt)
#pragma unroll
        for (int ks = 2; ks < 4; ++ks)
            afr[rt][ks] = *(const short8*)&qq[rt * 16 + lr][(ks - 2) * 32 + lg * 8];

    // Phase 1: scores; register ping-pong prefetch of B-fragments (K rows from L2).
    {
        const short* kr0 = kp + lr * 64 + lg * 8;
        const short* kkr0 = kk + lr * 64 + lg * 8;
        short8 bA[4], bB[4];
        {
            int off = (w * 16) * 16 * 64;
            bA[0] = *(const short8*)(kr0 + off);
            bA[1] = *(const short8*)(kr0 + off + 32);
            bA[2] = *(const short8*)(kkr0 + off);
            bA[3] = *(const short8*)(kkr0 + off + 32);
        }
#pragma unroll
        for (int ct = 0; ct < 16; ++ct) {
            short8* cur = (ct & 1) ? bB : bA;
            short8* nxt = (ct & 1) ? bA : bB;
            if (ct < 15) {
                int off = (w * 16 + ct + 1) * 16 * 64;
                nxt[0] = *(const short8*)(kr0 + off);
                nxt[1] = *(const short8*)(kr0 + off + 32);
                nxt[2] = *(const short8*)(kkr0 + off);
                nxt[3] = *(const short8*)(kkr0 + off + 32);
            }
            f32x4 a0 = (f32x4){0.f, 0.f, 0.f, 0.f};
            f32x4 a1 = (f32x4){0.f, 0.f, 0.f, 0.f};
#pragma unroll
            for (int ks = 0; ks < 4; ++ks) {
                a0 = MFMA16(afr[0][ks], cur[ks], a0);
                a1 = MFMA16(afr[1][ks], cur[ks], a1);
            }
            int c = (w * 16 + ct) * 16 + lr;
#pragma unroll
            for (int i = 0; i < 4; ++i) {
                S[sidx(lg * 4 + i, c)]      = f2b(a0[i]);
                S[sidx(16 + lg * 4 + i, c)] = f2b(a1[i]);
            }
        }
    }
    __syncthreads();

    // Phase 2: in-place row softmax.
    for (int r = w * 8; r < w * 8 + 8; ++r) {
        short8 c0 = *(short8*)&S[sidx(r, l * 8)];
        short8 c1 = *(short8*)&S[sidx(r, 512 + l * 8)];
        float v[16];
#pragma unroll
        for (int e = 0; e < 8; ++e) { v[e] = b2f(c0[e]); v[8 + e] = b2f(c1[e]); }
        float mx = v[0];
#pragma unroll
        for (int e = 1; e < 16; ++e) mx = fmaxf(mx, v[e]);
#pragma unroll
        for (int o = 1; o < 64; o <<= 1) mx = fmaxf(mx, __shfl_xor(mx, o));
        float sm = 0.f;
#pragma unroll
        for (int e = 0; e < 16; ++e) { v[e] = __expf(v[e] - mx); sm += v[e]; }
#pragma unroll
        for (int o = 1; o < 64; o <<= 1) sm += __shfl_xor(sm, o);
        float inv = 1.f / sm;
#pragma unroll
        for (int e = 0; e < 8; ++e) { c0[e] = f2b(v[e] * inv); c1[e] = f2b(v[8 + e] * inv); }
        *(short8*)&S[sidx(r, l * 8)] = c0;
        *(short8*)&S[sidx(r, 512 + l * 8)] = c1;
    }
    __syncthreads();

    // Phase 3: PV (K=1024), wave w owns output cols d0..d0+15; prefetch VT rows.
    int d0 = w * 16;
    f32x4 acc[2];
    acc[0] = (f32x4){0.f, 0.f, 0.f, 0.f};
    acc[1] = (f32x4){0.f, 0.f, 0.f, 0.f};
    {
        const short* vrow = vt + (d0 + lr) * 1024 + lg * 8;
        short8 vA = *(const short8*)(vrow);
        short8 vB;
#pragma unroll
        for (int ks = 0; ks < 32; ++ks) {
            short8 cur = (ks & 1) ? vB : vA;
            if (ks < 31) {
                if (ks & 1) vA = *(const short8*)(vrow + (ks + 1) * 32);
                else        vB = *(const short8*)(vrow + (ks + 1) * 32);
            }
#pragma unroll
            for (int rt = 0; rt < 2; ++rt) {
                short8 af = *(short8*)&S[sidx(rt * 16 + lr, ks * 32 + lg * 8)];
                acc[rt] = MFMA16(af, cur, acc[rt]);
            }
        }
    }
    int b = bh / 12, h = bh - b * 12;
#pragma unroll
    for (int rt = 0; rt < 2; ++rt)
#pragma unroll
        for (int i = 0; i < 4; ++i) {
            int n = r0 + rt * 16 + lg * 4 + i;
            out[(size_t)(b * 1024 + n) * 768 + h * 64 + d0 + lr] = acc[rt][i];
        }
}

extern "C" void kernel_launch(void* const* d_in, const int* in_sizes, int n_in,
                              void* d_out, int out_size, void* d_ws, size_t ws_size,
                              hipStream_t stream) {
    const float* x  = (const float*)d_in[0];
    const float* W  = (const float*)d_in[1];
    const float* qb = (const float*)d_in[2];
    const float* lg = (const float*)d_in[3];
    const float* lb = (const float*)d_in[4];
    float* out = (float*)d_out;
    char* ws = (char*)d_ws;
    // Workspace layout (peak 28,704,768 bytes):
    short* xnb = (short*)(ws + 0);         // [4096][768] bf16 (dead after gemm)
    short* Wb  = (short*)(ws + 6291456);   // [2304][768] bf16
    short* Qb  = (short*)(ws + 9830400);   // [48][1024][64] bf16, pre-scaled by 1.2/8
    short* Kb  = (short*)(ws + 16121856);  // [48][1024][64] bf16
    short* VT  = (short*)(ws + 22413312);  // [48][64][1024] bf16
    short* KK  = (short*)(ws + 0);         // [48][1024][64] bf16, overlays dead xnb

    hipLaunchKernelGGL(ln_kernel, dim3(4096), dim3(256), 0, stream, x, lg, lb, xnb);
    hipLaunchKernelGGL(wconv_kernel, dim3(1728), dim3(256), 0, stream, W, Wb);
    hipLaunchKernelGGL(qkv_gemm, dim3(32, 18), dim3(256), 0, stream, xnb, Wb, qb, Qb, Kb, VT);
    hipLaunchKernelGGL(kk_kernel, dim3(32, 48), dim3(256), 0, stream, Kb, KK);
    hipLaunchKernelGGL(attn_kernel, dim3(1536), dim3(256), 0, stream, Qb, Kb, KK, VT, out);
}